// Round 1
// baseline (1627.854 us; speedup 1.0000x reference)
//
#include <hip/hip_runtime.h>

typedef _Float16 f16;
typedef _Float16 half2t __attribute__((ext_vector_type(2)));
typedef _Float16 half8 __attribute__((ext_vector_type(8)));
typedef float floatx4 __attribute__((ext_vector_type(4)));

#define B_ 128
#define S_ 1024
#define D_ 256
#define H_ 256
#define N3H 768

// ---------------------------------------------------------------------------
// Pack W_hh fp32 [256][768] -> uint-packed half2 along K: whh2[k2*768 + j]
// holds (W[2k2][j], W[2k2+1][j]) as two fp16 in one dword.
// ---------------------------------------------------------------------------
__global__ void pack_whh_kernel(const float* __restrict__ whh,
                                unsigned int* __restrict__ whh2) {
  int idx = blockIdx.x * 256 + threadIdx.x;
  if (idx >= 128 * N3H) return;
  int k2 = idx / N3H;
  int j  = idx - k2 * N3H;
  f16 lo = (f16)whh[(2 * k2) * N3H + j];
  f16 hi = (f16)whh[(2 * k2 + 1) * N3H + j];
  unsigned int v = ((unsigned int)__builtin_bit_cast(unsigned short, lo)) |
                   ((unsigned int)__builtin_bit_cast(unsigned short, hi) << 16);
  whh2[idx] = v;
}

// ---------------------------------------------------------------------------
// Phase 1: gx[M=131072][768] = X[M][256] @ W_ih[256][768] + b_ih  (fp16 out)
// 128x128 block tile, 4 waves each computing 64x64 via 4x4 MFMA 16x16x32 f16.
// Converts fp32->fp16 while staging into LDS.
// ---------------------------------------------------------------------------
__global__ __launch_bounds__(256) void gemm_gx_kernel(
    const float* __restrict__ X, const float* __restrict__ W,
    const float* __restrict__ bias, f16* __restrict__ gx) {
  __shared__ __align__(16) f16 As[128][40];  // [m][k], pad 32->40
  __shared__ __align__(16) f16 Bs[128][40];  // [n][k] (transposed on store)
  const int m0 = blockIdx.x * 128;
  const int n0 = blockIdx.y * 128;
  const int tid = threadIdx.x;
  const int lane = tid & 63, wave = tid >> 6;
  const int wr = (wave >> 1) * 64, wc = (wave & 1) * 64;
  const int quad = lane >> 4, l16 = lane & 15;

  floatx4 acc[4][4];
#pragma unroll
  for (int i = 0; i < 4; i++)
#pragma unroll
    for (int j = 0; j < 4; j++) acc[i][j] = (floatx4)0.f;

  const int arow = tid >> 1, akh = (tid & 1) * 16;
  const int bkr = tid >> 3, bns = (tid & 7) * 16;

  for (int k0 = 0; k0 < 256; k0 += 32) {
    __syncthreads();
    {  // stage A: rows m0..m0+128, k0..k0+32
      const float* src = X + (size_t)(m0 + arow) * 256 + k0 + akh;
      float4 f0 = ((const float4*)src)[0];
      float4 f1 = ((const float4*)src)[1];
      float4 f2 = ((const float4*)src)[2];
      float4 f3 = ((const float4*)src)[3];
      half8 v0 = {(f16)f0.x, (f16)f0.y, (f16)f0.z, (f16)f0.w,
                  (f16)f1.x, (f16)f1.y, (f16)f1.z, (f16)f1.w};
      half8 v1 = {(f16)f2.x, (f16)f2.y, (f16)f2.z, (f16)f2.w,
                  (f16)f3.x, (f16)f3.y, (f16)f3.z, (f16)f3.w};
      *(half8*)&As[arow][akh] = v0;
      *(half8*)&As[arow][akh + 8] = v1;
    }
    {  // stage B transposed: W rows k0..k0+32, cols n0..n0+128 -> Bs[n][k]
      const float* src = W + (size_t)(k0 + bkr) * N3H + n0 + bns;
      float4 f0 = ((const float4*)src)[0];
      float4 f1 = ((const float4*)src)[1];
      float4 f2 = ((const float4*)src)[2];
      float4 f3 = ((const float4*)src)[3];
      float fv[16] = {f0.x, f0.y, f0.z, f0.w, f1.x, f1.y, f1.z, f1.w,
                      f2.x, f2.y, f2.z, f2.w, f3.x, f3.y, f3.z, f3.w};
#pragma unroll
      for (int i = 0; i < 16; ++i) Bs[bns + i][bkr] = (f16)fv[i];
    }
    __syncthreads();
    half8 a[4], b[4];
#pragma unroll
    for (int i = 0; i < 4; ++i) a[i] = *(const half8*)&As[wr + i * 16 + l16][quad * 8];
#pragma unroll
    for (int j = 0; j < 4; ++j) b[j] = *(const half8*)&Bs[wc + j * 16 + l16][quad * 8];
#pragma unroll
    for (int i = 0; i < 4; ++i)
#pragma unroll
      for (int j = 0; j < 4; ++j)
        acc[i][j] = __builtin_amdgcn_mfma_f32_16x16x32_f16(a[i], b[j], acc[i][j], 0, 0, 0);
  }
#pragma unroll
  for (int i = 0; i < 4; ++i) {
#pragma unroll
    for (int j = 0; j < 4; ++j) {
      int col = n0 + wc + j * 16 + l16;
      float bv = bias[col];
#pragma unroll
      for (int r = 0; r < 4; ++r) {
        int row = m0 + wr + i * 16 + quad * 4 + r;
        gx[(size_t)row * N3H + col] = (f16)(acc[i][j][r] + bv);
      }
    }
  }
}

// ---------------------------------------------------------------------------
// Phase 2: sequential GRU recurrence. One block per batch element (sync-free
// across blocks). 768 threads; thread j owns gh column j with its 256 fp16
// W_hh weights register-resident (128 packed dwords). h lives in LDS (fp16),
// broadcast-read each step; fp32 accumulation via v_dot2_f32_f16.
// ---------------------------------------------------------------------------
__global__ __launch_bounds__(768) void gru_rec_kernel(
    const f16* __restrict__ gx,           // [128*1024][768]
    const unsigned int* __restrict__ w2,  // [128][768] packed half2
    const float* __restrict__ bhh,        // [768]
    const float* __restrict__ mask,       // [128][1024]
    float* __restrict__ out) {            // [128][1024][256]
  const int b = blockIdx.x;
  const int j = threadIdx.x;
  __shared__ __align__(16) f16 h16[256];
  __shared__ float rz[512];

  unsigned int w[128];
#pragma unroll
  for (int k2 = 0; k2 < 128; ++k2) w[k2] = w2[k2 * N3H + j];

  if (j < 256) h16[j] = (f16)0.f;
  const float bj = bhh[j];
  const f16* gxp = gx + (size_t)b * S_ * N3H + j;
  const float* mp = mask + (size_t)b * S_;
  float* outp = out + (size_t)b * S_ * H_;

  __syncthreads();

  f16 cur_gx = gxp[0];
  float cur_m = mp[0];
  for (int t = 0; t < S_; ++t) {
    f16 nxt_gx = (f16)0.f;
    float nxt_m = 0.f;
    if (t + 1 < S_) {
      nxt_gx = gxp[(size_t)(t + 1) * N3H];
      nxt_m = mp[t + 1];
    }
    float acc = 0.f;
    const uint4* h4 = (const uint4*)h16;
#pragma unroll
    for (int c = 0; c < 32; ++c) {
      uint4 hc = h4[c];
      acc = __builtin_amdgcn_fdot2(__builtin_bit_cast(half2t, hc.x),
                                   __builtin_bit_cast(half2t, w[c * 4 + 0]), acc, false);
      acc = __builtin_amdgcn_fdot2(__builtin_bit_cast(half2t, hc.y),
                                   __builtin_bit_cast(half2t, w[c * 4 + 1]), acc, false);
      acc = __builtin_amdgcn_fdot2(__builtin_bit_cast(half2t, hc.z),
                                   __builtin_bit_cast(half2t, w[c * 4 + 2]), acc, false);
      acc = __builtin_amdgcn_fdot2(__builtin_bit_cast(half2t, hc.w),
                                   __builtin_bit_cast(half2t, w[c * 4 + 3]), acc, false);
    }
    float gh = acc + bj;
    float gxv = (float)cur_gx;
    if (j < 512) {  // r (0..255) and z (256..511) gates — wave-uniform branch
      float xa = gxv + gh;
      xa = fminf(fmaxf(xa, -30.f), 30.f);
      rz[j] = 1.f / (1.f + __expf(-xa));
    }
    __syncthreads();
    if (j >= 512) {  // n gate + state update — wave-uniform branch
      const int jj = j - 512;
      float r = rz[jj], z = rz[jj + 256];
      float xn = gxv + r * gh;
      xn = fminf(fmaxf(xn, -15.f), 15.f);
      float e = __expf(2.f * xn);
      float n = (e - 1.f) / (e + 1.f);  // tanh
      float hp = (float)h16[jj];
      float hn = (1.f - z) * n + z * hp;
      float hv = cur_m * hn + (1.f - cur_m) * hp;
      h16[jj] = (f16)hv;
      outp[(size_t)t * H_ + jj] = hv;
    }
    __syncthreads();
    cur_gx = nxt_gx;
    cur_m = nxt_m;
  }
}

// ---------------------------------------------------------------------------
extern "C" void kernel_launch(void* const* d_in, const int* in_sizes, int n_in,
                              void* d_out, int out_size, void* d_ws, size_t ws_size,
                              hipStream_t stream) {
  const float* x    = (const float*)d_in[0];
  const float* mask = (const float*)d_in[1];
  const float* Wih  = (const float*)d_in[2];
  const float* Whh  = (const float*)d_in[3];
  const float* bih  = (const float*)d_in[4];
  const float* bhh  = (const float*)d_in[5];
  float* out = (float*)d_out;

  // ws layout: gx16 (201.3 MB) | whh2 packed (384 KB)
  f16* gx = (f16*)d_ws;
  unsigned int* whh2 =
      (unsigned int*)((char*)d_ws + (size_t)B_ * S_ * N3H * sizeof(f16));

  pack_whh_kernel<<<dim3((128 * N3H + 255) / 256), dim3(256), 0, stream>>>(Whh, whh2);
  gemm_gx_kernel<<<dim3((B_ * S_) / 128, N3H / 128), dim3(256), 0, stream>>>(x, Wih, bih, gx);
  gru_rec_kernel<<<dim3(B_), dim3(768), 0, stream>>>(gx, whh2, bhh, mask, out);
}